// Round 6
// baseline (299.953 us; speedup 1.0000x reference)
//
#include <hip/hip_runtime.h>
#include <stdint.h>

// RelationalNetwork B=8 C=64 O=256 TE=128 GT=FP=256 A=32
// R6: PERSISTENT k_main. 256 blocks, (256,1) -> 512 VGPR/wave. Each wave
// holds its 64-col slices of W2^T AND W3^T in registers (256 VGPR) for the
// whole kernel -> K-loops have zero memory traffic (R5 showed per-tile
// blocks re-read 256KB of weights from L2 -> ~1GB L2 traffic = the wall).
// Two 32KB LDS h-buffers ping-pong: build(t+1) overlaps GEMM1(t).
// Swizzle: chunk ^ (row&7) on 256-stride (bank-verified free in all 3
// phases; SQ_LDS_BANK_CONFLICT ~5.26M is the structural b128 floor).
// k_pre rewritten (256 blocks, LDS-staged x/code, coalesced w1 stream).

#define NPAIR 32896
#define NTILE 514
#define NTOT  4112           // 8 * NTILE

using short8  = __attribute__((ext_vector_type(8))) short;
using float4v = __attribute__((ext_vector_type(4))) float;

__device__ __forceinline__ float    asf(unsigned u){ union{unsigned u; float f;}c; c.u=u; return c.f; }
__device__ __forceinline__ unsigned asu(float f){ union{float f; unsigned u;}c; c.f=f; return c.u; }
__device__ __forceinline__ unsigned short f2bf(float f){
    unsigned u = asu(f); u += 0x7FFFu + ((u>>16)&1u); return (unsigned short)(u>>16);
}
__device__ __forceinline__ unsigned pkhu(float lo, float hi){
    return __builtin_amdgcn_perm(asu(hi)+0x8000u, asu(lo)+0x8000u, 0x07060302u);
}
__device__ __forceinline__ unsigned bfar2(unsigned u, unsigned v){
    float sh = fmaxf(asf(u & 0xffff0000u) + asf(v & 0xffff0000u), 0.f);
    float sl = fmaxf(asf(u << 16)         + asf(v << 16),         0.f);
    return pkhu(sl, sh);
}

// ---- prep: blocks 0..255 U/V (i=block, all 8 batches per thread);
//      blocks 256..287 W2/W3 transpose+bf16 --------------------------------
__global__ __launch_bounds__(256) void k_pre(
    const float* __restrict__ x, const float* __restrict__ code,
    const float* __restrict__ w1, const float* __restrict__ b1,
    const float* __restrict__ w2, const float* __restrict__ w3,
    unsigned short* __restrict__ ub, unsigned short* __restrict__ vb,
    unsigned short* __restrict__ w2t, unsigned short* __restrict__ w3t)
{
    const int bx = blockIdx.x, tid = threadIdx.x;
    if (bx < 256) {
        __shared__ float xs[512];    // x[b][c][i] for this i
        __shared__ float cs[1024];   // code, all batches
        const int i = bx;
        #pragma unroll
        for (int t = tid; t < 512; t += 256)
            xs[t] = x[t * 256 + i];                    // t = b*64+c
        #pragma unroll
        for (int t = tid; t < 1024; t += 256) cs[t] = code[t];
        __syncthreads();
        const int d = tid;
        float su[8], sv[8];
        #pragma unroll
        for (int b = 0; b < 8; ++b) { su[b] = 0.f; sv[b] = 0.f; }
        #pragma unroll 4
        for (int t = 0; t < 128; ++t) {
            float wq = w1[(132 + t) * 256 + d];
            #pragma unroll
            for (int b = 0; b < 8; ++b) su[b] += cs[b * 128 + t] * wq;
        }
        #pragma unroll 2
        for (int c = 0; c < 64; ++c) {
            float wa = w1[c * 256 + d];
            float wb = w1[(66 + c) * 256 + d];
            #pragma unroll
            for (int b = 0; b < 8; ++b) {
                float xv = xs[b * 64 + c];
                su[b] += xv * wa;
                sv[b] += xv * wb;
            }
        }
        float yy = (float)(i >> 4) * (2.f / 15.f) - 1.f;
        float xx = (float)(i & 15) * (2.f / 15.f) - 1.f;
        float cu = yy * w1[64 * 256 + d]  + xx * w1[65 * 256 + d] + b1[d];
        float cv = yy * w1[130 * 256 + d] + xx * w1[131 * 256 + d];
        #pragma unroll
        for (int b = 0; b < 8; ++b) {
            ub[(b * 256 + i) * 256 + d] = f2bf(su[b] + cu);
            vb[(b * 256 + i) * 256 + d] = f2bf(sv[b] + cv);
        }
    } else {
        __shared__ float t[64][65];
        const int id = bx - 256;
        const float* src = (id >= 16) ? w3 : w2;
        unsigned short* dst = (id >= 16) ? w3t : w2t;
        const int rem = id & 15;
        const int k0 = (rem >> 2) * 64, n0 = (rem & 3) * 64;
        const int tx = tid & 63, ty = tid >> 6;
        #pragma unroll
        for (int r = ty; r < 64; r += 4)
            t[r][tx] = src[(k0 + r) * 256 + n0 + tx];
        __syncthreads();
        #pragma unroll
        for (int r = ty; r < 64; r += 4)
            dst[(n0 + r) * 256 + k0 + tx] = f2bf(t[tx][r]);
    }
}

#define LOADA(dst, tb, ksv) { \
    _Pragma("unroll") \
    for (int mt = 0; mt < 4; ++mt) \
        dst[mt] = *(const short8*)(&(tb)[(mt * 16 + lm) * 256 + \
                                   ((((ksv) * 4 + quad) ^ (lm & 7)) << 3)]); }
#define MFMA16(bv, av) { \
    _Pragma("unroll") \
    for (int mt = 0; mt < 4; ++mt) \
        _Pragma("unroll") \
        for (int nt = 0; nt < 4; ++nt) \
            acc[mt][nt] = __builtin_amdgcn_mfma_f32_16x16x32_bf16( \
                av[mt], bv[nt], acc[mt][nt], 0, 0, 0); }

// ---- persistent fused g_theta L2+L3 + tril row-sum -----------------------
__global__ __launch_bounds__(256, 1) void k_main(
    const unsigned short* __restrict__ ub, const unsigned short* __restrict__ vb,
    const unsigned short* __restrict__ w2t, const unsigned short* __restrict__ w3t,
    const float* __restrict__ b2, const float* __restrict__ b3,
    float* __restrict__ part)
{
    __shared__ unsigned short buf[2][64 * 256];    // 2 x 32 KiB ping-pong
    const int tid  = threadIdx.x;
    const int lane = tid & 63, wave = tid >> 6;
    const int n0   = wave * 64;
    const int lm   = lane & 15, quad = lane >> 4;
    const int r    = tid >> 2, q4 = tid & 3;       // build role: 4 thr/row

    // ---- W2^T / W3^T wave-slices -> registers, once ----
    short8 B2[8][4], B3[8][4];
    {
        const unsigned short* bb2 = w2t + (n0 + lm) * 256 + quad * 8;
        const unsigned short* bb3 = w3t + (n0 + lm) * 256 + quad * 8;
        #pragma unroll
        for (int ks = 0; ks < 8; ++ks)
            #pragma unroll
            for (int nt = 0; nt < 4; ++nt) {
                B2[ks][nt] = *(const short8*)(bb2 + nt * 4096 + ks * 32);
                B3[ks][nt] = *(const short8*)(bb3 + nt * 4096 + ks * 32);
            }
    }
    float b2c[4], b3c[4];
    #pragma unroll
    for (int nt = 0; nt < 4; ++nt) {
        b2c[nt] = b2[n0 + nt * 16 + lm];
        b3c[nt] = b3[n0 + nt * 16 + lm];
    }

    int tl = blockIdx.x;           // linear tile id
    int bcur = 0, t = tl;          // batch / in-batch tile (tl < 256 < NTILE)

    // ---- build tile0 into buf[0] ----
    {
        const int pn = t * 64 + r;
        float sq = sqrtf(8.f * (float)pn + 1.f);
        int ii = (int)((sq - 1.f) * 0.5f);
        while ((ii + 1) * (ii + 2) / 2 <= pn) ++ii;
        while (ii * (ii + 1) / 2 > pn) --ii;
        const int jj = pn - ii * (ii + 1) / 2;
        const uint4* up = (const uint4*)(ub + (bcur * 256 + ii) * 256);
        const uint4* vp = (const uint4*)(vb + (bcur * 256 + jj) * 256);
        #pragma unroll
        for (int it = 0; it < 8; ++it) {
            const int c = it * 4 + q4;
            uint4 u = up[c], v = vp[c];
            uint4 w;
            w.x = bfar2(u.x, v.x); w.y = bfar2(u.y, v.y);
            w.z = bfar2(u.z, v.z); w.w = bfar2(u.w, v.w);
            *(uint4*)(&buf[0][r * 256 + ((c ^ (r & 7)) << 3)]) = w;
        }
    }
    __syncthreads();

    int p = 0;
    while (true) {
        const int  tl2      = tl + 256;
        const bool has_next = (tl2 < NTOT);
        int b2i = bcur, t2 = t + 256;
        if (t2 >= NTILE) { t2 -= NTILE; ++b2i; }

        // ---- next-tile (i,j) + first-half u/v prefetch ----
        const uint4* up2 = nullptr; const uint4* vp2 = nullptr;
        uint4 u0[4], v0[4];
        if (has_next) {
            const int pn = t2 * 64 + r;
            float sq = sqrtf(8.f * (float)pn + 1.f);
            int ii = (int)((sq - 1.f) * 0.5f);
            while ((ii + 1) * (ii + 2) / 2 <= pn) ++ii;
            while (ii * (ii + 1) / 2 > pn) --ii;
            const int jj = pn - ii * (ii + 1) / 2;
            up2 = (const uint4*)(ub + (b2i * 256 + ii) * 256);
            vp2 = (const uint4*)(vb + (b2i * 256 + jj) * 256);
            #pragma unroll
            for (int it = 0; it < 4; ++it) {
                u0[it] = up2[it * 4 + q4];
                v0[it] = vp2[it * 4 + q4];
            }
        }

        const unsigned short* tb = buf[p];
        const float4v zero4 = {0.f, 0.f, 0.f, 0.f};
        float4v acc[4][4];
        #pragma unroll
        for (int mt = 0; mt < 4; ++mt)
            #pragma unroll
            for (int nt = 0; nt < 4; ++nt) acc[mt][nt] = zero4;

        // ---- GEMM1: h2 = h1 @ W2 (B in registers) ----
        {
            short8 aA[4], aB[4];
            LOADA(aA, tb, 0);
            #pragma unroll
            for (int ks = 0; ks < 8; ks += 2) {
                LOADA(aB, tb, ks + 1);
                MFMA16(B2[ks], aA);
                if (ks + 2 < 8) LOADA(aA, tb, ks + 2);
                MFMA16(B2[ks + 1], aB);
            }
        }

        // ---- build(t+1) into the other buffer ----
        if (has_next) {
            unsigned short* ob = buf[1 - p];
            uint4 u1[4], v1[4];
            #pragma unroll
            for (int it = 0; it < 4; ++it) {
                u1[it] = up2[(it + 4) * 4 + q4];
                v1[it] = vp2[(it + 4) * 4 + q4];
            }
            #pragma unroll
            for (int it = 0; it < 4; ++it) {
                const int c = it * 4 + q4;
                uint4 w;
                w.x = bfar2(u0[it].x, v0[it].x); w.y = bfar2(u0[it].y, v0[it].y);
                w.z = bfar2(u0[it].z, v0[it].z); w.w = bfar2(u0[it].w, v0[it].w);
                *(uint4*)(&ob[r * 256 + ((c ^ (r & 7)) << 3)]) = w;
            }
            #pragma unroll
            for (int it = 4; it < 8; ++it) {
                const int c = it * 4 + q4;
                uint4 w;
                w.x = bfar2(u1[it-4].x, v1[it-4].x); w.y = bfar2(u1[it-4].y, v1[it-4].y);
                w.z = bfar2(u1[it-4].z, v1[it-4].z); w.w = bfar2(u1[it-4].w, v1[it-4].w);
                *(uint4*)(&ob[r * 256 + ((c ^ (r & 7)) << 3)]) = w;
            }
        }
        __syncthreads();

        // ---- h2 = relu(acc + b2) -> buf[p] (paired b32, swizzled) ----
        {
            unsigned short* wbuf = buf[p];
            #pragma unroll
            for (int mt = 0; mt < 4; ++mt) {
                #pragma unroll
                for (int nt = 0; nt < 4; ++nt) {
                    const int colE = n0 + nt * 16 + (lm & ~1);
                    #pragma unroll
                    for (int rg = 0; rg < 4; ++rg) {
                        const int row = mt * 16 + quad * 4 + rg;
                        float v  = fmaxf(acc[mt][nt][rg] + b2c[nt], 0.f);
                        float v1 = __shfl_down(v, 1);
                        if (!(lm & 1))
                            wbuf[row * 256 + ((((colE >> 3) ^ (row & 7)) << 3) | (colE & 7))]
                                = (unsigned short)(pkhu(v, v1) & 0xFFFFu),
                            *(unsigned*)(&wbuf[row * 256 +
                                ((((colE >> 3) ^ (row & 7)) << 3) | (colE & 7))]) = pkhu(v, v1);
                    }
                }
            }
        }
        __syncthreads();

        // ---- GEMM2: rel = h2 @ W3 (B in registers) ----
        #pragma unroll
        for (int mt = 0; mt < 4; ++mt)
            #pragma unroll
            for (int nt = 0; nt < 4; ++nt) acc[mt][nt] = zero4;
        {
            short8 aA[4], aB[4];
            LOADA(aA, tb, 0);
            #pragma unroll
            for (int ks = 0; ks < 8; ks += 2) {
                LOADA(aB, tb, ks + 1);
                MFMA16(B3[ks], aA);
                if (ks + 2 < 8) LOADA(aA, tb, ks + 2);
                MFMA16(B3[ks + 1], aB);
            }
        }

        // ---- relu + row-sum -> coalesced partials ----
        #pragma unroll
        for (int nt = 0; nt < 4; ++nt) {
            float s = 0.f;
            #pragma unroll
            for (int mt = 0; mt < 4; ++mt)
                #pragma unroll
                for (int rg = 0; rg < 4; ++rg)
                    s += fmaxf(acc[mt][nt][rg] + b3c[nt], 0.f);
            s += __shfl_xor(s, 16);
            s += __shfl_xor(s, 32);
            if (quad == 0)
                part[((size_t)(bcur * NTILE + t)) * 256 + n0 + nt * 16 + lm] = s;
        }

        if (!has_next) return;
        __syncthreads();
        tl = tl2; bcur = b2i; t = t2; p ^= 1;
    }
}

// ---- reduce partials + f_phi, 1024 threads (4-way K-split) ---------------
__global__ __launch_bounds__(1024) void k_tail(
    const float* __restrict__ part,
    const float* __restrict__ fw1, const float* __restrict__ fb1,
    const float* __restrict__ fw2, const float* __restrict__ fb2,
    const float* __restrict__ fw3, const float* __restrict__ fb3,
    float* __restrict__ out)
{
    __shared__ float red[4 * 256];
    __shared__ float s0[256], s1[256];
    const int b = blockIdx.x;
    const int d = threadIdx.x & 255, seg = threadIdx.x >> 8;

    float s = 0.f;
    const float* pp = part + (size_t)b * NTILE * 256 + d;
    #pragma unroll 8
    for (int t = seg; t < NTILE; t += 4) s += pp[t * 256];
    red[seg * 256 + d] = s;
    __syncthreads();
    if (seg == 0) s0[d] = red[d] + red[256 + d] + red[512 + d] + red[768 + d];
    __syncthreads();

    float a = 0.f;
    #pragma unroll 8
    for (int k = seg * 64; k < seg * 64 + 64; ++k) a += s0[k] * fw1[k * 256 + d];
    red[seg * 256 + d] = a;
    __syncthreads();
    if (seg == 0)
        s1[d] = fmaxf(red[d] + red[256 + d] + red[512 + d] + red[768 + d] + fb1[d], 0.f);
    __syncthreads();

    a = 0.f;
    #pragma unroll 8
    for (int k = seg * 64; k < seg * 64 + 64; ++k) a += s1[k] * fw2[k * 256 + d];
    red[seg * 256 + d] = a;
    __syncthreads();
    if (seg == 0)
        s0[d] = fmaxf(red[d] + red[256 + d] + red[512 + d] + red[768 + d] + fb2[d], 0.f);
    __syncthreads();

    if (d < 32) {
        float o = 0.f;
        #pragma unroll 8
        for (int k = seg * 64; k < seg * 64 + 64; ++k) o += s0[k] * fw3[k * 32 + d];
        red[seg * 256 + d] = o;
    }
    __syncthreads();
    if (seg == 0 && d < 32)
        out[b * 32 + d] = red[d] + red[256 + d] + red[512 + d] + red[768 + d] + fb3[d];
}

extern "C" void kernel_launch(void* const* d_in, const int* in_sizes, int n_in,
                              void* d_out, int out_size, void* d_ws, size_t ws_size,
                              hipStream_t stream) {
    const float* x    = (const float*)d_in[0];
    const float* code = (const float*)d_in[1];
    const float* gw1  = (const float*)d_in[2];
    const float* gb1  = (const float*)d_in[3];
    const float* gw2  = (const float*)d_in[4];
    const float* gb2  = (const float*)d_in[5];
    const float* gw3  = (const float*)d_in[6];
    const float* gb3  = (const float*)d_in[7];
    const float* fw1  = (const float*)d_in[8];
    const float* fb1  = (const float*)d_in[9];
    const float* fw2  = (const float*)d_in[10];
    const float* fb2  = (const float*)d_in[11];
    const float* fw3  = (const float*)d_in[12];
    const float* fb3  = (const float*)d_in[13];
    float* out = (float*)d_out;

    char* ws = (char*)d_ws;
    unsigned short* ub  = (unsigned short*)(ws);               // 1 MiB
    unsigned short* vb  = (unsigned short*)(ws + 1048576);     // 1 MiB
    unsigned short* w2t = (unsigned short*)(ws + 2097152);     // 128 KiB
    unsigned short* w3t = (unsigned short*)(ws + 2228224);     // 128 KiB
    float*          part= (float*)(ws + 2359296);              // 4,210,688 B

    hipLaunchKernelGGL(k_pre, dim3(288), dim3(256), 0, stream,
                       x, code, gw1, gb1, gw2, gw3, ub, vb, w2t, w3t);
    hipLaunchKernelGGL(k_main, dim3(256), dim3(256), 0, stream,
                       ub, vb, w2t, w3t, gb2, gb3, part);
    hipLaunchKernelGGL(k_tail, dim3(8), dim3(1024), 0, stream,
                       part, fw1, fb1, fw2, fb2, fw3, fb3, out);
}